// Round 6
// baseline (797.715 us; speedup 1.0000x reference)
//
#include <hip/hip_runtime.h>
#include <stdint.h>

typedef _Float16 half8 __attribute__((ext_vector_type(8)));
typedef float float4v __attribute__((ext_vector_type(4)));

#define H_IN 256
#define W_IN 256
#define H_OUT 254
#define W_OUT 254
#define T_COLS 68
#define A_ROWS 408   // 6 rows * 68 cols

// ---------------------------------------------------------------------------
// Pack conv_weight (OIHW fp32) into coalesced-fragment layout:
//   Bp2[g][co][q][e]  with g = (kh*3+kw)*2 + h,  cin = h*32 + q*8 + e
// One wave's fragment load (16 co x 4 q x 8 e) = 1 KB contiguous.
// ---------------------------------------------------------------------------
__global__ void pack_w_kernel(const float* __restrict__ w, _Float16* __restrict__ Bp2) {
    int idx = blockIdx.x * 256 + threadIdx.x;          // 128*576 = 73728
    if (idx >= 128 * 576) return;
    int co  = idx / 576;
    int kp  = idx - co * 576;
    int tap = kp >> 6;
    int cin = kp & 63;
    int kh  = tap / 3, kw = tap - kh * 3;
    int h   = cin >> 5;
    int q   = (cin >> 3) & 3;
    int e   = cin & 7;
    int g   = tap * 2 + h;
    Bp2[((((size_t)g * 128 + co) * 4) + q) * 8 + e] =
        (_Float16)w[(co * 64 + cin) * 9 + kh * 3 + kw];
}

// Swizzle key: spreads BOTH read pattern (16 consecutive rows) and staging
// write pattern (rows stride 4) across 8 distinct 16B slots -> <=2-way (free).
__device__ __forceinline__ int akey(int row) {
    return (((row & 7) ^ ((row >> 3) & 7)) << 4);
}

// ---------------------------------------------------------------------------
// v6: persistent row-strip conv + bias + min_c + tanh(tanh(.)).
// 1 block/CU-ish (launch_bounds(256,1), ~400 VGPR): ILP replaces TLP.
// grid (4,8,16) = 512 blocks; each block: 8 tiles of 4 output rows x 64 cols.
// Per tile: issue 26 fp32 staging loads for tile t+1 EARLY (T14), compute
// 18 (tap,h) groups with depth-1 A-LDS and depth-2 B-L2 register pipelines,
// epilogue, then cvt+LDS-write the prefetched tile.
// ---------------------------------------------------------------------------
__global__ __launch_bounds__(256, 1)
void conv_v6_kernel(const float* __restrict__ x,
                    const _Float16* __restrict__ Bp2,
                    const float* __restrict__ bias,
                    float* __restrict__ out) {
    __shared__ __align__(16) _Float16 Alds[A_ROWS * 64];   // 52224 B
    __shared__ float minbuf[2][256];

    const int tid  = threadIdx.x;
    const int lane = tid & 63;
    const int wave = tid >> 6;
    const int ow0  = blockIdx.x * 64;
    const int ohb  = blockIdx.y * 32;
    const int nb   = blockIdx.z;
    const int wr   = wave >> 1;
    const int wc   = wave & 1;
    const int q    = lane >> 4;
    const int lr   = lane & 15;

    const float* xb = x + (size_t)nb * (64 * H_IN * W_IN);

    // ---- staging descriptors: item id = tid + 256k (id < 816)
    // item = 8 cin (one octet) x 4 px (one col-quad); 17 quads x 6 rows x 8 octs
    int  s_oct[4], s_row0[4], s_r[4], s_iw[4];
    bool s_val[4];
#pragma unroll
    for (int k = 0; k < 4; ++k) {
        int id   = tid + 256 * k;
        s_val[k] = (id < 816);
        int o    = (unsigned)id / 102u;
        int pxq  = id - o * 102;
        int r    = (unsigned)pxq / 17u;
        int c4   = (pxq - r * 17) * 4;
        s_oct[k]  = o;
        s_row0[k] = pxq * 4;
        s_r[k]    = r;
        int iw = ow0 + c4;
        if (iw > W_IN - 4) iw = W_IN - 4;   // clamp (cols >=64 only feed masked px)
        s_iw[k] = iw;
    }

    float4v fr[4][8];   // staging registers (4 px x 8 cin per item)

    auto stage_load = [&](int ih0) {
#pragma unroll
        for (int k = 0; k < 4; ++k) {
            if (!s_val[k]) continue;
            int ih = ih0 + s_r[k];
            if (ih > H_IN - 1) ih = H_IN - 1;
            const float* src = xb + (size_t)(s_oct[k] * 8) * (H_IN * W_IN)
                                  + (size_t)ih * W_IN + s_iw[k];
#pragma unroll
            for (int u = 0; u < 8; ++u)
                fr[k][u] = *(const float4v*)(src + (size_t)u * (H_IN * W_IN));
        }
    };
    auto stage_write = [&]() {
#pragma unroll
        for (int k = 0; k < 4; ++k) {
            if (!s_val[k]) continue;
#pragma unroll
            for (int j = 0; j < 4; ++j) {
                int row = s_row0[k] + j;
                half8 hv;
#pragma unroll
                for (int u = 0; u < 8; ++u) hv[u] = (_Float16)fr[k][u][j];
                *(half8*)((char*)Alds + row * 128 + ((s_oct[k] * 16) ^ akey(row))) = hv;
            }
        }
    };

    float bv[4];
#pragma unroll
    for (int n = 0; n < 4; ++n) bv[n] = bias[wc * 64 + n * 16 + lr];

    const char* bp0 = (const char*)Bp2 + (size_t)(wc * 64 + lr) * 64 + q * 16;
    const int rb = wr * 136 + lr;   // wr*2*T_COLS + lr

    auto loadA = [&](int gg, half8 (&dst)[8]) {
        const int tap = gg >> 1, hh = gg & 1;
        const int kh = tap / 3, kw = tap - kh * 3;
        const int kb = hh * 64 + q * 16;
#pragma unroll
        for (int m = 0; m < 8; ++m) {
            int row = rb + ((m >> 2) + kh) * T_COLS + (m & 3) * 16 + kw;
            dst[m] = *(const half8*)((const char*)Alds + row * 128 + (kb ^ akey(row)));
        }
    };

    // ---- prologue: tile 0 into LDS
    stage_load(ohb);
    stage_write();
    __syncthreads();

    for (int t = 0; t < 8; ++t) {
        // issue next tile's global loads EARLY; results consumed after compute
        if (t < 7) stage_load(ohb + (t + 1) * 4);
        __builtin_amdgcn_sched_barrier(0);   // don't sink the loads past compute

        float4v acc[8][4];
#pragma unroll
        for (int m = 0; m < 8; ++m)
#pragma unroll
            for (int n = 0; n < 4; ++n)
#pragma unroll
                for (int i = 0; i < 4; ++i) acc[m][n][i] = 0.0f;

        half8 a[2][8];
        half8 b[3][4];
#pragma unroll
        for (int n = 0; n < 4; ++n) b[0][n] = *(const half8*)(bp0 + 0 * 8192 + n * 1024);
#pragma unroll
        for (int n = 0; n < 4; ++n) b[1][n] = *(const half8*)(bp0 + 1 * 8192 + n * 1024);
        loadA(0, a[0]);

#pragma unroll
        for (int g = 0; g < 18; ++g) {
            if (g < 16) {
#pragma unroll
                for (int n = 0; n < 4; ++n)
                    b[(g + 2) % 3][n] =
                        *(const half8*)(bp0 + (size_t)(g + 2) * 8192 + n * 1024);
            }
            if (g < 17) loadA(g + 1, a[(g + 1) & 1]);
#pragma unroll
            for (int m = 0; m < 8; ++m)
#pragma unroll
                for (int n = 0; n < 4; ++n)
                    acc[m][n] = __builtin_amdgcn_mfma_f32_16x16x32_f16(
                        a[g & 1][m], b[g % 3][n], acc[m][n], 0, 0, 0);
        }

        // ---- epilogue: + bias, min over channels, publish per-px min
        const int oh0 = ohb + t * 4;
#pragma unroll
        for (int m = 0; m < 8; ++m) {
            float4v v;
#pragma unroll
            for (int n = 0; n < 4; ++n) {
#pragma unroll
                for (int i = 0; i < 4; ++i) {
                    float tt = acc[m][n][i] + bv[n];
                    v[i] = (n == 0) ? tt : fminf(v[i], tt);
                }
            }
#pragma unroll
            for (int off = 1; off < 16; off <<= 1)
#pragma unroll
                for (int i = 0; i < 4; ++i)
                    v[i] = fminf(v[i], __shfl_xor(v[i], off, 64));
            if (lr == 0) {
#pragma unroll
                for (int i = 0; i < 4; ++i)
                    minbuf[wc][wr * 128 + m * 16 + q * 4 + i] = v[i];
            }
        }
        __syncthreads();
        {
            int r = tid >> 6, c = tid & 63;
            int oh = oh0 + r, ow = ow0 + c;
            if (oh < H_OUT && ow < W_OUT) {
                float mv = fminf(minbuf[0][tid], minbuf[1][tid]);
                out[((size_t)nb * H_OUT + oh) * W_OUT + ow] = tanhf(tanhf(mv));
            }
        }
        // cvt + write prefetched tile into LDS (Alds free: all reads done pre-barrier)
        if (t < 7) stage_write();
        __syncthreads();
    }
}

extern "C" void kernel_launch(void* const* d_in, const int* in_sizes, int n_in,
                              void* d_out, int out_size, void* d_ws, size_t ws_size,
                              hipStream_t stream) {
    const float* x    = (const float*)d_in[0];
    const float* w    = (const float*)d_in[1];
    const float* bias = (const float*)d_in[2];
    float* out        = (float*)d_out;
    _Float16* Bp2     = (_Float16*)d_ws;   // 147456 B

    pack_w_kernel<<<dim3(288), dim3(256), 0, stream>>>(w, Bp2);
    conv_v6_kernel<<<dim3(4, 8, 16), dim3(256), 0, stream>>>(x, Bp2, bias, out);
}

// Round 7
// 175.640 us; speedup vs baseline: 4.5418x; 4.5418x over previous
//
#include <hip/hip_runtime.h>
#include <stdint.h>

typedef _Float16 half8 __attribute__((ext_vector_type(8)));
typedef float float4v __attribute__((ext_vector_type(4)));

#define H_IN 256
#define W_IN 256
#define H_OUT 254
#define W_OUT 254
#define T_COLS 68
#define A_ROWS 408   // 6 rows * 68 cols
#define A_BYTES (A_ROWS * 128)          // 52224
#define B_BYTES (2 * 8192)              // double-buffered group slab
#define MIN_BYTES (2 * 256 * 4)
#define SMEM_BYTES (A_BYTES + B_BYTES + MIN_BYTES)   // 70656

// ---------------------------------------------------------------------------
// Pack conv_weight (OIHW fp32) into DMA-ready, pre-swizzled layout:
//   Bp3[g][co][s16][e], g=(kh*3+kw)*2+h, s16 = q ^ (co&3), cin = h*32+q*8+e.
// A linear 8 KB DMA of slab g into LDS gives Blds[co*64 + s16*16] such that
// the read  slot = q ^ (co&3)  recovers cin-octet q -> bank-floor reads.
// ---------------------------------------------------------------------------
__global__ void pack_w_kernel(const float* __restrict__ w, _Float16* __restrict__ Bp3) {
    int idx = blockIdx.x * 256 + threadIdx.x;   // 18*4096 = 73728
    if (idx >= 73728) return;
    int g   = idx >> 12;
    int rem = idx & 4095;
    int co  = rem >> 5;
    int s16 = (rem >> 3) & 3;
    int e   = rem & 7;
    int q   = s16 ^ (co & 3);
    int tap = g >> 1, h = g & 1;
    int cin = h * 32 + q * 8 + e;
    int kh  = tap / 3, kw = tap - kh * 3;
    Bp3[idx] = (_Float16)w[(co * 64 + cin) * 9 + kh * 3 + kw];
}

// A-tile swizzle key: floor-optimal for consecutive-row reads AND stride-4
// staging writes.
__device__ __forceinline__ int akey(int row) {
    return (((row & 7) ^ ((row >> 3) & 7)) << 4);
}

// ---------------------------------------------------------------------------
// v7: 512 threads, 8 waves of 64px x 64co (acc=64 VGPR -> 4 waves/SIMD).
// A (52 KB) staged once per block (reg-transpose of NCHW fp32 -> [px][cin] fp16).
// B staged per (tap,h) group into 2x8KB LDS ring via ONE global_load_lds
// dwordx4 per thread (no VGPR cost, unsinkable), shared by all 8 waves.
// 1 barrier/group; second co-resident block covers the sync.
// grid (4, 64, 16), dynamic LDS 70656 B.
// ---------------------------------------------------------------------------
__global__ __launch_bounds__(512, 4)
void conv_v7_kernel(const float* __restrict__ x,
                    const _Float16* __restrict__ Bp3,
                    const float* __restrict__ bias,
                    float* __restrict__ out) {
    extern __shared__ __align__(16) char smem[];
    char*  Alds   = smem;                        // [408 rows][128 B] swizzled
    char*  Blds   = smem + A_BYTES;              // [2][8192 B]
    float* minbuf = (float*)(smem + A_BYTES + B_BYTES);   // [2][256]

    const int tid  = threadIdx.x;
    const int lane = tid & 63;
    const int wave = tid >> 6;      // 0..7
    const int ow0  = blockIdx.x * 64;
    const int oh0  = blockIdx.y * 4;
    const int nb   = blockIdx.z;
    const int wr   = wave >> 1;     // output row within tile (0..3)
    const int wc   = wave & 1;      // co half
    const int q    = lane >> 4;
    const int lr   = lane & 15;

    // ---- issue B[0] DMA (1 instr/thread)
    {
        const char* src = (const char*)Bp3 + tid * 16;
        char* dstb = Blds + (tid & ~63) * 16;
        __builtin_amdgcn_global_load_lds(
            (const __attribute__((address_space(1))) uint32_t*)src,
            (__attribute__((address_space(3))) uint32_t*)dstb, 16, 0, 0);
    }

    // ---- stage A tile: 816 items (8cin x 4px each), reg-transpose, swizzled write
    {
        const float* xb = x + (size_t)nb * (64 * H_IN * W_IN);
#pragma unroll
        for (int k = 0; k < 2; ++k) {
            int id = tid + 512 * k;
            if (id < 816) {
                int oct  = (unsigned)id / 102u;
                int pxq  = id - oct * 102;
                int row0 = pxq * 4;
                int r    = (unsigned)row0 / (unsigned)T_COLS;
                int c    = row0 - r * T_COLS;
                int ih   = oh0 + r; if (ih > H_IN - 1) ih = H_IN - 1;
                int iw   = ow0 + c; if (iw > W_IN - 4) iw = W_IN - 4;
                const float* src = xb + (size_t)(oct * 8) * (H_IN * W_IN)
                                      + (size_t)ih * W_IN + iw;
                float4v f[8];
#pragma unroll
                for (int u = 0; u < 8; ++u)
                    f[u] = *(const float4v*)(src + (size_t)u * (H_IN * W_IN));
#pragma unroll
                for (int j = 0; j < 4; ++j) {
                    int row = row0 + j;
                    half8 hv;
#pragma unroll
                    for (int u = 0; u < 8; ++u) hv[u] = (_Float16)f[u][j];
                    *(half8*)(Alds + row * 128 + ((oct * 16) ^ akey(row))) = hv;
                }
            }
        }
    }

    float bv[4];
#pragma unroll
    for (int n = 0; n < 4; ++n) bv[n] = bias[wc * 64 + n * 16 + lr];

    float4v acc[4][4];
#pragma unroll
    for (int m = 0; m < 4; ++m)
#pragma unroll
        for (int n = 0; n < 4; ++n)
#pragma unroll
            for (int i = 0; i < 4; ++i) acc[m][n][i] = 0.0f;

    const int bslot = (q ^ (lr & 3)) << 4;          // B read slot (pre-swizzled pack)
    const int bco   = (wc * 64 + lr) * 64;          // +n*16*64 per frag

#pragma unroll
    for (int g = 0; g < 18; ++g) {
        // barrier: ends group g-1 (all reads of buf (g+1)&1 done; DMA of buf g&1 landed)
        __syncthreads();

        if (g < 17) {   // issue next group's B DMA into the other buffer
            const char* src = (const char*)Bp3 + (size_t)(g + 1) * 8192 + tid * 16;
            char* dstb = Blds + ((g + 1) & 1) * 8192 + (tid & ~63) * 16;
            __builtin_amdgcn_global_load_lds(
                (const __attribute__((address_space(1))) uint32_t*)src,
                (__attribute__((address_space(3))) uint32_t*)dstb, 16, 0, 0);
        }

        const int tap = g >> 1, h = g & 1;
        const int kh = tap / 3, kw = tap - kh * 3;
        const int kb = h * 64 + q * 16;

        half8 a[4], b[4];
#pragma unroll
        for (int n = 0; n < 4; ++n)
            b[n] = *(const half8*)(Blds + (g & 1) * 8192 + bco + n * 1024 + bslot);
#pragma unroll
        for (int m = 0; m < 4; ++m) {
            int row = (wr + kh) * T_COLS + m * 16 + lr + kw;
            a[m] = *(const half8*)(Alds + row * 128 + (kb ^ akey(row)));
        }
#pragma unroll
        for (int m = 0; m < 4; ++m)
#pragma unroll
            for (int n = 0; n < 4; ++n)
                acc[m][n] = __builtin_amdgcn_mfma_f32_16x16x32_f16(
                    a[m], b[n], acc[m][n], 0, 0, 0);
    }

    // ---- epilogue: + bias, min over co, double tanh
#pragma unroll
    for (int m = 0; m < 4; ++m) {
        float4v v;
#pragma unroll
        for (int n = 0; n < 4; ++n) {
#pragma unroll
            for (int i = 0; i < 4; ++i) {
                float t = acc[m][n][i] + bv[n];
                v[i] = (n == 0) ? t : fminf(v[i], t);
            }
        }
#pragma unroll
        for (int off = 1; off < 16; off <<= 1)
#pragma unroll
            for (int i = 0; i < 4; ++i)
                v[i] = fminf(v[i], __shfl_xor(v[i], off, 64));
        if (lr == 0) {
#pragma unroll
            for (int i = 0; i < 4; ++i)
                minbuf[wc * 256 + wr * 64 + m * 16 + q * 4 + i] = v[i];
        }
    }
    __syncthreads();

    if (tid < 256) {
        int r = tid >> 6, c = tid & 63;
        int oh = oh0 + r, ow = ow0 + c;
        if (oh < H_OUT && ow < W_OUT) {
            float mv = fminf(minbuf[tid], minbuf[256 + tid]);
            out[((size_t)nb * H_OUT + oh) * W_OUT + ow] = tanhf(tanhf(mv));
        }
    }
}

extern "C" void kernel_launch(void* const* d_in, const int* in_sizes, int n_in,
                              void* d_out, int out_size, void* d_ws, size_t ws_size,
                              hipStream_t stream) {
    const float* x    = (const float*)d_in[0];
    const float* w    = (const float*)d_in[1];
    const float* bias = (const float*)d_in[2];
    float* out        = (float*)d_out;
    _Float16* Bp3     = (_Float16*)d_ws;   // 147456 B

    pack_w_kernel<<<dim3(288), dim3(256), 0, stream>>>(w, Bp3);
    conv_v7_kernel<<<dim3(4, 64, 16), dim3(512), SMEM_BYTES, stream>>>(x, Bp3, bias, out);
}

// Round 8
// 168.627 us; speedup vs baseline: 4.7306x; 1.0416x over previous
//
#include <hip/hip_runtime.h>
#include <stdint.h>

typedef _Float16 half8 __attribute__((ext_vector_type(8)));
typedef float float4v __attribute__((ext_vector_type(4)));

#define H_IN 256
#define W_IN 256
#define H_OUT 254
#define W_OUT 254
#define T_COLS 68
#define A_ROWS 408   // 6 rows * 68 cols
#define A_BYTES (A_ROWS * 128)          // 52224
#define B_SLAB  8192
#define B_BYTES (3 * B_SLAB)            // ring of 3 group slabs
#define MIN_BYTES (2 * 256 * 4)
#define SMEM_BYTES (A_BYTES + B_BYTES + MIN_BYTES)   // 78848 -> 2 blocks/CU

// ---------------------------------------------------------------------------
// Pack conv_weight (OIHW fp32) into DMA-ready, bank-floor-swizzled layout:
//   Bp3[g][co][s16][e], g=(kh*3+kw)*2+h, s16 = q ^ ((co>>2)&3), cin=h*32+q*8+e
// Linear 8 KB DMA per slab; read slot q ^ ((lr>>2)&3) gives <=2-way banks
// (v7's q^(co&3) was 4-way at the 16-lane phase level -> 23M conflict cycles).
// ---------------------------------------------------------------------------
__global__ void pack_w_kernel(const float* __restrict__ w, _Float16* __restrict__ Bp3) {
    int idx = blockIdx.x * 256 + threadIdx.x;   // 18*4096 = 73728
    if (idx >= 73728) return;
    int g   = idx >> 12;
    int rem = idx & 4095;
    int co  = rem >> 5;
    int s16 = (rem >> 3) & 3;
    int e   = rem & 7;
    int q   = s16 ^ ((co >> 2) & 3);
    int tap = g >> 1, h = g & 1;
    int cin = h * 32 + q * 8 + e;
    int kh  = tap / 3, kw = tap - kh * 3;
    Bp3[idx] = (_Float16)w[(co * 64 + cin) * 9 + kh * 3 + kw];
}

// A-tile swizzle key: floor for consecutive-row reads AND stride-4 staging writes.
__device__ __forceinline__ int akey(int row) {
    return (((row & 7) ^ ((row >> 3) & 7)) << 4);
}

// ---------------------------------------------------------------------------
// v8: v7 geometry (8 waves x 64px x 64co, A staged once, B slab per group)
// + T3/T4: B ring-3, counted s_waitcnt vmcnt(1) + RAW s_barrier per group
//   (no vmcnt(0)/lgkmcnt(0) drain in the main loop), DMA for slab g+2 issued
//   after barrier g (ring-3 race-free: slab (g+2)%3's readers ended at
//   barrier g).  + T5 setprio around the MFMA cluster.
// grid (4, 64, 16), 512 threads, dynamic LDS 78848 B.
// ---------------------------------------------------------------------------
__global__ __launch_bounds__(512, 4)
void conv_v8_kernel(const float* __restrict__ x,
                    const _Float16* __restrict__ Bp3,
                    const float* __restrict__ bias,
                    float* __restrict__ out) {
    extern __shared__ __align__(16) char smem[];
    char*  Alds   = smem;                               // [408 rows][128 B]
    char*  Blds   = smem + A_BYTES;                     // [3][8192 B]
    float* minbuf = (float*)(smem + A_BYTES + B_BYTES); // [2][256]

    const int tid  = threadIdx.x;
    const int lane = tid & 63;
    const int wave = tid >> 6;      // 0..7
    const int ow0  = blockIdx.x * 64;
    const int oh0  = blockIdx.y * 4;
    const int nb   = blockIdx.z;
    const int wr   = wave >> 1;     // output row within tile (0..3)
    const int wc   = wave & 1;      // co half
    const int q    = lane >> 4;
    const int lr   = lane & 15;

    // ---- issue B slab 0 and 1 DMAs (1 instr each per thread)
#pragma unroll
    for (int s = 0; s < 2; ++s) {
        const char* src = (const char*)Bp3 + s * B_SLAB + tid * 16;
        char* dstb = Blds + s * B_SLAB + (tid & ~63) * 16;
        __builtin_amdgcn_global_load_lds(
            (const __attribute__((address_space(1))) uint32_t*)src,
            (__attribute__((address_space(3))) uint32_t*)dstb, 16, 0, 0);
    }

    float bv[4];
#pragma unroll
    for (int n = 0; n < 4; ++n) bv[n] = bias[wc * 64 + n * 16 + lr];

    // ---- stage A tile: 816 items (8cin x 4px each), reg-transpose, swizzled
    {
        const float* xb = x + (size_t)nb * (64 * H_IN * W_IN);
#pragma unroll
        for (int k = 0; k < 2; ++k) {
            int id = tid + 512 * k;
            if (id < 816) {
                int oct  = (unsigned)id / 102u;
                int pxq  = id - oct * 102;
                int row0 = pxq * 4;
                int r    = (unsigned)row0 / (unsigned)T_COLS;
                int c    = row0 - r * T_COLS;
                int ih   = oh0 + r; if (ih > H_IN - 1) ih = H_IN - 1;
                int iw   = ow0 + c; if (iw > W_IN - 4) iw = W_IN - 4;
                const float* src = xb + (size_t)(oct * 8) * (H_IN * W_IN)
                                      + (size_t)ih * W_IN + iw;
                float4v f[8];
#pragma unroll
                for (int u = 0; u < 8; ++u)
                    f[u] = *(const float4v*)(src + (size_t)u * (H_IN * W_IN));
#pragma unroll
                for (int j = 0; j < 4; ++j) {
                    int row = row0 + j;
                    half8 hv;
#pragma unroll
                    for (int u = 0; u < 8; ++u) hv[u] = (_Float16)f[u][j];
                    *(half8*)(Alds + row * 128 + ((oct * 16) ^ akey(row))) = hv;
                }
            }
        }
    }
    __syncthreads();   // A visible; slab0/1 DMAs still (possibly) in flight

    float4v acc[4][4];
#pragma unroll
    for (int m = 0; m < 4; ++m)
#pragma unroll
        for (int n = 0; n < 4; ++n)
#pragma unroll
            for (int i = 0; i < 4; ++i) acc[m][n][i] = 0.0f;

    const int bslot = (q ^ ((lr >> 2) & 3)) << 4;   // bank-floor read slot
    const int bco   = (wc * 64 + lr) * 64;          // +n*1024 per frag

#pragma unroll
    for (int g = 0; g < 18; ++g) {
        // ---- T4: counted wait (slab g landed in *my* wave), raw barrier
        // (all waves passed their wait => slab g fully written). No drain.
        if (g < 17) asm volatile("s_waitcnt vmcnt(1)" ::: "memory");
        else        asm volatile("s_waitcnt vmcnt(0)" ::: "memory");
        __builtin_amdgcn_s_barrier();
        __builtin_amdgcn_sched_barrier(0);

        // ---- issue DMA for slab g+2 (safe: slab (g+2)%3's last readers
        // finished before barrier g)
        if (g < 16) {
            const char* src = (const char*)Bp3 + (size_t)(g + 2) * B_SLAB + tid * 16;
            char* dstb = Blds + ((g + 2) % 3) * B_SLAB + (tid & ~63) * 16;
            __builtin_amdgcn_global_load_lds(
                (const __attribute__((address_space(1))) uint32_t*)src,
                (__attribute__((address_space(3))) uint32_t*)dstb, 16, 0, 0);
        }

        const int tap = g >> 1, h = g & 1;
        const int kh = tap / 3, kw = tap - kh * 3;
        const int kb = h * 64 + q * 16;

        half8 a[4], b[4];
#pragma unroll
        for (int n = 0; n < 4; ++n)
            b[n] = *(const half8*)(Blds + (g % 3) * B_SLAB + bco + n * 1024 + bslot);
#pragma unroll
        for (int m = 0; m < 4; ++m) {
            int row = (wr + kh) * T_COLS + m * 16 + lr + kw;
            a[m] = *(const half8*)(Alds + row * 128 + (kb ^ akey(row)));
        }

        __builtin_amdgcn_s_setprio(1);
#pragma unroll
        for (int m = 0; m < 4; ++m)
#pragma unroll
            for (int n = 0; n < 4; ++n)
                acc[m][n] = __builtin_amdgcn_mfma_f32_16x16x32_f16(
                    a[m], b[n], acc[m][n], 0, 0, 0);
        __builtin_amdgcn_s_setprio(0);
    }

    // ---- epilogue: + bias, min over co, double tanh
#pragma unroll
    for (int m = 0; m < 4; ++m) {
        float4v v;
#pragma unroll
        for (int n = 0; n < 4; ++n) {
#pragma unroll
            for (int i = 0; i < 4; ++i) {
                float t = acc[m][n][i] + bv[n];
                v[i] = (n == 0) ? t : fminf(v[i], t);
            }
        }
#pragma unroll
        for (int off = 1; off < 16; off <<= 1)
#pragma unroll
            for (int i = 0; i < 4; ++i)
                v[i] = fminf(v[i], __shfl_xor(v[i], off, 64));
        if (lr == 0) {
#pragma unroll
            for (int i = 0; i < 4; ++i)
                minbuf[wc * 256 + wr * 64 + m * 16 + q * 4 + i] = v[i];
        }
    }
    __syncthreads();

    if (tid < 256) {
        int r = tid >> 6, c = tid & 63;
        int oh = oh0 + r, ow = ow0 + c;
        if (oh < H_OUT && ow < W_OUT) {
            float mv = fminf(minbuf[tid], minbuf[256 + tid]);
            out[((size_t)nb * H_OUT + oh) * W_OUT + ow] = tanhf(tanhf(mv));
        }
    }
}

extern "C" void kernel_launch(void* const* d_in, const int* in_sizes, int n_in,
                              void* d_out, int out_size, void* d_ws, size_t ws_size,
                              hipStream_t stream) {
    const float* x    = (const float*)d_in[0];
    const float* w    = (const float*)d_in[1];
    const float* bias = (const float*)d_in[2];
    float* out        = (float*)d_out;
    _Float16* Bp3     = (_Float16*)d_ws;   // 147456 B

    pack_w_kernel<<<dim3(288), dim3(256), 0, stream>>>(w, Bp3);
    conv_v8_kernel<<<dim3(4, 64, 16), dim3(512), SMEM_BYTES, stream>>>(x, Bp3, bias, out);
}